// Round 4
// baseline (974.019 us; speedup 1.0000x reference)
//
#include <hip/hip_runtime.h>
#include <hip/hip_bf16.h>

// MultiDecoder: per-articulator MLP 12->128->256->200 over 32768 tokens, A=10.
// bf16 MFMA (16x16x32) for layers 2/3; layer 1 (K=12) in fp32 VALU.
// R3: phase-3 output staged in LDS -> contiguous float4 row stores.
// R4 (measured): nt stores + a-slowest grid -> WRITE 1.74->2.47 GB, dur 644->686.
//     Lesson: write amplification comes from 800B records (32B line-misaligned)
//     whose boundary lines are shared by blocks on DIFFERENT XCDs; nt stores
//     forward partial fragments straight to memory.
// R7: single-writer-per-line restructure: one block owns 64 tokens x ALL 10
//     articulators (a-loop inside block). Block's output = contiguous,
//     64B-aligned 512KB region -> every line fully written by one block in one
//     L2 -> writebacks collapse to ~262MB. x tile read once (L2-hit for a>0).
//     Normal stores (L2 merges the intra-block 32B record boundaries).
// ws needed: 1,720,320 bytes.

#define A_   10
#define C_   12
#define H2_  128
#define H_   256
#define F_   200
#define NT3  13      // ceil(208/16) N-tiles for layer 3 (padded)
#define BT_  32768
#define L_   120
#define TT   64      // tokens per block

typedef __attribute__((ext_vector_type(8))) short short8;
typedef __attribute__((ext_vector_type(8))) __bf16 bf16x8;
typedef __attribute__((ext_vector_type(4))) float floatx4;

__device__ inline floatx4 mfma16x16x32(short8 a, short8 b, floatx4 c) {
    return __builtin_amdgcn_mfma_f32_16x16x32_bf16(
        __builtin_bit_cast(bf16x8, a), __builtin_bit_cast(bf16x8, b), c, 0, 0, 0);
}

__device__ inline short f2bf(float f) {
    union { float f; unsigned u; } v; v.f = f;
    unsigned r = v.u + 0x7fffu + ((v.u >> 16) & 1u);  // RTN-even
    return (short)(r >> 16);
}

// B-fragment order for mfma_f32_16x16x32_bf16: lane holds B[k=(lane>>4)*8+j][n=lane&15].
// w2sw: [a][nt(16)][ks(4)][lane(64)][j(8)]
// w3sw: [a][nt(13)][ks(8)][lane(64)][j(8)]  (N padded to 208)
__global__ void swizzle_weights(const float* __restrict__ W2,
                                const float* __restrict__ W3,
                                short* __restrict__ w2sw,
                                short* __restrict__ w3sw) {
    int id = blockIdx.x * blockDim.x + threadIdx.x;
    const int NW2 = A_ * 16 * 4 * 64;   // 40960
    const int NW3 = A_ * NT3 * 8 * 64;  // 66560
    if (id < NW2) {
        int lane = id & 63;
        int ks   = (id >> 6) & 3;
        int nt   = (id >> 8) & 15;
        int a    = id >> 12;
        int n  = nt * 16 + (lane & 15);
        int k0 = ks * 32 + (lane >> 4) * 8;
        short8 v;
#pragma unroll
        for (int j = 0; j < 8; ++j)
            v[j] = f2bf(W2[(a * H2_ + (k0 + j)) * H_ + n]);
        *(short8*)&w2sw[(size_t)id * 8] = v;
    } else if (id < NW2 + NW3) {
        int id3 = id - NW2;
        int lane = id3 & 63;
        int ks   = (id3 >> 6) & 7;
        int nt   = (id3 >> 9) % NT3;
        int a    = id3 / (64 * 8 * NT3);
        int n  = nt * 16 + (lane & 15);
        int k0 = ks * 32 + (lane >> 4) * 8;
        short8 v;
#pragma unroll
        for (int j = 0; j < 8; ++j)
            v[j] = (n < F_) ? f2bf(W3[(a * H_ + (k0 + j)) * F_ + n]) : (short)0;
        *(short8*)&w3sw[(size_t)id3 * 8] = v;
    }
}

__global__ __launch_bounds__(256, 3)
void multidecoder_kernel(const float* __restrict__ x,
                         const float* __restrict__ W1,
                         const float* __restrict__ b1,
                         const float* __restrict__ b2,
                         const float* __restrict__ b3,
                         const int*   __restrict__ idx,
                         const short* __restrict__ w2sw,
                         const short* __restrict__ w3sw,
                         float* __restrict__ out) {
    // h1[64][136]s (17408 B) + h2[64][264]s (33792 B) overlaid with
    // outbuf[64][204]f (52224 B). s_x[64][12]f (3072 B) overlays the FIRST
    // 3072 B of the h2 region: s_x is consumed in phase 1 (which only writes
    // h1) and dead before phase 2 writes h2. Row strides keep 16B alignment
    // and <=2-way bank aliasing (free). Total LDS 52224 -> 3 blocks/CU.
    __shared__ char smem[52224] __attribute__((aligned(16)));
    short (*s_h1)[136] = (short(*)[136])smem;
    short (*s_h2)[264] = (short(*)[264])(smem + 17408);
    float (*s_ob)[204] = (float(*)[204])smem;
    float (*s_x)[12]   = (float(*)[12])(smem + 17408);

    const int tid  = threadIdx.x;
    const int lane = tid & 63;
    const int wv   = tid >> 6;
    const int t0   = blockIdx.x * TT;   // block owns tokens t0..t0+63, ALL articulators

#pragma unroll 1
    for (int a = 0; a < A_; ++a) {

        // ---- Phase 0: gather x tile [64 tokens][12 comps] into LDS ----
        // a==0 misses to HBM (~30KB region); a>0 hits L2 (same block, same XCD).
        for (int i = tid; i < TT * C_; i += 256) {
            int t = i / C_, c = i - t * C_;
            int col = idx[a * C_ + c];
            s_x[t][c] = x[(size_t)(t0 + t) * L_ + col];
        }
        __syncthreads();

        // ---- Phase 1: h1 = relu(x @ W1 + b1), fp32 VALU, -> bf16 LDS ----
        {
            int h  = (tid & 63) * 2;
            int tg = tid >> 6;
            float2 w1c[12];
#pragma unroll
            for (int c = 0; c < C_; ++c)
                w1c[c] = *(const float2*)&W1[(a * C_ + c) * H2_ + h];
            float bb0 = b1[a * H2_ + h];
            float bb1 = b1[a * H2_ + h + 1];
#pragma unroll
            for (int tt = 0; tt < 16; ++tt) {
                int t = tg * 16 + tt;
                const floatx4* xr = (const floatx4*)&s_x[t][0];
                float acc0 = bb0, acc1 = bb1;
#pragma unroll
                for (int cc = 0; cc < 3; ++cc) {
                    floatx4 xv = xr[cc];
#pragma unroll
                    for (int jj = 0; jj < 4; ++jj) {
                        float xs = xv[jj];
                        acc0 = fmaf(xs, w1c[cc * 4 + jj].x, acc0);
                        acc1 = fmaf(xs, w1c[cc * 4 + jj].y, acc1);
                    }
                }
                acc0 = fmaxf(acc0, 0.f);
                acc1 = fmaxf(acc1, 0.f);
                unsigned pk = (unsigned short)f2bf(acc0) |
                              ((unsigned)(unsigned short)f2bf(acc1) << 16);
                *(unsigned*)&s_h1[t][h] = pk;
            }
        }
        __syncthreads();

        // ---- Phase 2: h2 = relu(h1 @ W2 + b2), MFMA, -> bf16 LDS ----
        {
            floatx4 acc[4][4] = {};
            int row  = lane & 15;
            int quad = lane >> 4;
#pragma unroll
            for (int ks = 0; ks < 4; ++ks) {
                int koff = ks * 32 + quad * 8;
                short8 afr[4];
#pragma unroll
                for (int mt = 0; mt < 4; ++mt)
                    afr[mt] = *(const short8*)&s_h1[mt * 16 + row][koff];
                short8 bfr[4];
#pragma unroll
                for (int nl = 0; nl < 4; ++nl) {
                    int nt = wv * 4 + nl;
                    bfr[nl] = *(const short8*)&w2sw[(size_t)(((a * 16 + nt) * 4 + ks) * 64 + lane) * 8];
                }
#pragma unroll
                for (int mt = 0; mt < 4; ++mt)
#pragma unroll
                    for (int nl = 0; nl < 4; ++nl)
                        acc[mt][nl] = mfma16x16x32(afr[mt], bfr[nl], acc[mt][nl]);
            }
            // D: col = lane&15, row = quad*4 + r
#pragma unroll
            for (int nl = 0; nl < 4; ++nl) {
                int col = (wv * 4 + nl) * 16 + row;
                float bias = b2[a * H_ + col];
#pragma unroll
                for (int mt = 0; mt < 4; ++mt)
#pragma unroll
                    for (int r = 0; r < 4; ++r) {
                        int trow = mt * 16 + quad * 4 + r;
                        float v = acc[mt][nl][r] + bias;
                        s_h2[trow][col] = f2bf(fmaxf(v, 0.f));
                    }
            }
        }
        __syncthreads();

        // ---- Phase 3: out = h2 @ W3 + b3, MFMA -> LDS staging ----
        {
            int nts[4] = { wv, wv + 4, wv + 8, 12 };
            int nnt = (wv == 0) ? 4 : 3;
            int row  = lane & 15;
            int quad = lane >> 4;
            floatx4 acc[4][4] = {};
            for (int ks = 0; ks < 8; ++ks) {
                int koff = ks * 32 + quad * 8;
                short8 afr[4];
#pragma unroll
                for (int mt = 0; mt < 4; ++mt)
                    afr[mt] = *(const short8*)&s_h2[mt * 16 + row][koff];
                for (int q = 0; q < nnt; ++q) {
                    int nt = nts[q];
                    short8 bfr = *(const short8*)&w3sw[(size_t)(((a * NT3 + nt) * 8 + ks) * 64 + lane) * 8];
#pragma unroll
                    for (int mt = 0; mt < 4; ++mt)
                        acc[mt][q] = mfma16x16x32(afr[mt], bfr, acc[mt][q]);
                }
            }
            __syncthreads();   // all h2 reads done; smem is reused as outbuf below

            for (int q = 0; q < nnt; ++q) {
                int nt = nts[q];
                int col = nt * 16 + row;
                if (col < F_) {
                    float bias = b3[a * F_ + col];
#pragma unroll
                    for (int mt = 0; mt < 4; ++mt)
#pragma unroll
                        for (int r = 0; r < 4; ++r) {
                            int trow = mt * 16 + quad * 4 + r;
                            s_ob[trow][col] = acc[mt][q][r] + bias;
                        }
                }
            }
        }
        __syncthreads();

        // ---- Phase 4: cooperative contiguous store: 64 rows x 200 floats ----
        // Normal (allocating) stores: all record-boundary partial lines are
        // owned by THIS block's L2 and merge with the neighboring a's writes.
        for (int i = tid; i < TT * 50; i += 256) {
            int t  = i / 50;
            int c4 = (i - t * 50) * 4;
            floatx4 v = *(const floatx4*)&s_ob[t][c4];
            *(floatx4*)&out[((size_t)(t0 + t) * A_ + a) * F_ + c4] = v;
        }
        __syncthreads();   // s_ob fully consumed before next a's gather overwrites smem
    }
}

extern "C" void kernel_launch(void* const* d_in, const int* in_sizes, int n_in,
                              void* d_out, int out_size, void* d_ws, size_t ws_size,
                              hipStream_t stream) {
    (void)in_sizes; (void)n_in; (void)out_size; (void)ws_size;
    const float* x  = (const float*)d_in[0];
    const float* W1 = (const float*)d_in[1];
    const float* b1 = (const float*)d_in[2];
    const float* W2 = (const float*)d_in[3];
    const float* b2 = (const float*)d_in[4];
    const float* W3 = (const float*)d_in[5];
    const float* b3 = (const float*)d_in[6];
    const int*   idx = (const int*)d_in[7];
    float* out = (float*)d_out;

    short* w2sw = (short*)d_ws;                                  // 655,360 B
    short* w3sw = w2sw + (size_t)A_ * 16 * 4 * 64 * 8;           // +1,064,960 B

    const int nconv = A_ * 16 * 4 * 64 + A_ * NT3 * 8 * 64;      // 107,520
    swizzle_weights<<<dim3((nconv + 255) / 256), dim3(256), 0, stream>>>(W2, W3, w2sw, w3sw);
    multidecoder_kernel<<<dim3(BT_ / TT), dim3(256), 0, stream>>>(
        x, W1, b1, b2, b3, idx, w2sw, w3sw, out);
}

// Round 5
// 494.206 us; speedup vs baseline: 1.9709x; 1.9709x over previous
//
#include <hip/hip_runtime.h>
#include <hip/hip_bf16.h>

// MultiDecoder: per-articulator MLP 12->128->256->200 over 32768 tokens, A=10.
// bf16 MFMA (16x16x32) for layers 2/3; layer 1 (K=12) in fp32 VALU.
// R7 (measured): block owns 64 tokens x all 10 articulators; WRITE still 2.06GB
//     (~8x output) regardless of store scheme -> store path is NOT the source.
// R8: ROOT CAUSE: phase-3 q-loop had RUNTIME bound (nnt=3/4) -> acc[4][4]
//     runtime-indexed -> compiler allocates accumulators in SCRATCH; every
//     MFMA did a 32B scratch RMW (~4.4GB of EA traffic, the mystery WRITE).
//     Fix: compile-time structure: acc[4][3] with unrolled q=0..2 (nt=wv+4q),
//     separate acc3[4] for tile 12 under wave-uniform if(wv==0). No nts[].
// ws needed: 1,720,320 bytes.

#define A_   10
#define C_   12
#define H2_  128
#define H_   256
#define F_   200
#define NT3  13      // ceil(208/16) N-tiles for layer 3 (padded)
#define BT_  32768
#define L_   120
#define TT   64      // tokens per block

typedef __attribute__((ext_vector_type(8))) short short8;
typedef __attribute__((ext_vector_type(8))) __bf16 bf16x8;
typedef __attribute__((ext_vector_type(4))) float floatx4;

__device__ inline floatx4 mfma16x16x32(short8 a, short8 b, floatx4 c) {
    return __builtin_amdgcn_mfma_f32_16x16x32_bf16(
        __builtin_bit_cast(bf16x8, a), __builtin_bit_cast(bf16x8, b), c, 0, 0, 0);
}

__device__ inline short f2bf(float f) {
    union { float f; unsigned u; } v; v.f = f;
    unsigned r = v.u + 0x7fffu + ((v.u >> 16) & 1u);  // RTN-even
    return (short)(r >> 16);
}

// B-fragment order for mfma_f32_16x16x32_bf16: lane holds B[k=(lane>>4)*8+j][n=lane&15].
// w2sw: [a][nt(16)][ks(4)][lane(64)][j(8)]
// w3sw: [a][nt(13)][ks(8)][lane(64)][j(8)]  (N padded to 208)
__global__ void swizzle_weights(const float* __restrict__ W2,
                                const float* __restrict__ W3,
                                short* __restrict__ w2sw,
                                short* __restrict__ w3sw) {
    int id = blockIdx.x * blockDim.x + threadIdx.x;
    const int NW2 = A_ * 16 * 4 * 64;   // 40960
    const int NW3 = A_ * NT3 * 8 * 64;  // 66560
    if (id < NW2) {
        int lane = id & 63;
        int ks   = (id >> 6) & 3;
        int nt   = (id >> 8) & 15;
        int a    = id >> 12;
        int n  = nt * 16 + (lane & 15);
        int k0 = ks * 32 + (lane >> 4) * 8;
        short8 v;
#pragma unroll
        for (int j = 0; j < 8; ++j)
            v[j] = f2bf(W2[(a * H2_ + (k0 + j)) * H_ + n]);
        *(short8*)&w2sw[(size_t)id * 8] = v;
    } else if (id < NW2 + NW3) {
        int id3 = id - NW2;
        int lane = id3 & 63;
        int ks   = (id3 >> 6) & 7;
        int nt   = (id3 >> 9) % NT3;
        int a    = id3 / (64 * 8 * NT3);
        int n  = nt * 16 + (lane & 15);
        int k0 = ks * 32 + (lane >> 4) * 8;
        short8 v;
#pragma unroll
        for (int j = 0; j < 8; ++j)
            v[j] = (n < F_) ? f2bf(W3[(a * H_ + (k0 + j)) * F_ + n]) : (short)0;
        *(short8*)&w3sw[(size_t)id3 * 8] = v;
    }
}

__global__ __launch_bounds__(256, 3)
void multidecoder_kernel(const float* __restrict__ x,
                         const float* __restrict__ W1,
                         const float* __restrict__ b1,
                         const float* __restrict__ b2,
                         const float* __restrict__ b3,
                         const int*   __restrict__ idx,
                         const short* __restrict__ w2sw,
                         const short* __restrict__ w3sw,
                         float* __restrict__ out) {
    // h1[64][136]s (17408 B) + h2[64][264]s (33792 B) overlaid with
    // outbuf[64][204]f (52224 B). s_x[64][12]f (3072 B) overlays the FIRST
    // 3072 B of the h2 region: s_x is consumed in phase 1 (which only writes
    // h1) and dead before phase 2 writes h2. Total LDS 52224.
    __shared__ char smem[52224] __attribute__((aligned(16)));
    short (*s_h1)[136] = (short(*)[136])smem;
    short (*s_h2)[264] = (short(*)[264])(smem + 17408);
    float (*s_ob)[204] = (float(*)[204])smem;
    float (*s_x)[12]   = (float(*)[12])(smem + 17408);

    const int tid  = threadIdx.x;
    const int lane = tid & 63;
    const int wv   = tid >> 6;
    const int t0   = blockIdx.x * TT;   // block owns tokens t0..t0+63, ALL articulators

#pragma unroll 1
    for (int a = 0; a < A_; ++a) {

        // ---- Phase 0: gather x tile [64 tokens][12 comps] into LDS ----
        for (int i = tid; i < TT * C_; i += 256) {
            int t = i / C_, c = i - t * C_;
            int col = idx[a * C_ + c];
            s_x[t][c] = x[(size_t)(t0 + t) * L_ + col];
        }
        __syncthreads();

        // ---- Phase 1: h1 = relu(x @ W1 + b1), fp32 VALU, -> bf16 LDS ----
        {
            int h  = (tid & 63) * 2;
            int tg = tid >> 6;
            float2 w1c[12];
#pragma unroll
            for (int c = 0; c < C_; ++c)
                w1c[c] = *(const float2*)&W1[(a * C_ + c) * H2_ + h];
            float bb0 = b1[a * H2_ + h];
            float bb1 = b1[a * H2_ + h + 1];
#pragma unroll
            for (int tt = 0; tt < 16; ++tt) {
                int t = tg * 16 + tt;
                const floatx4* xr = (const floatx4*)&s_x[t][0];
                float acc0 = bb0, acc1 = bb1;
#pragma unroll
                for (int cc = 0; cc < 3; ++cc) {
                    floatx4 xv = xr[cc];
#pragma unroll
                    for (int jj = 0; jj < 4; ++jj) {
                        float xs = xv[jj];
                        acc0 = fmaf(xs, w1c[cc * 4 + jj].x, acc0);
                        acc1 = fmaf(xs, w1c[cc * 4 + jj].y, acc1);
                    }
                }
                acc0 = fmaxf(acc0, 0.f);
                acc1 = fmaxf(acc1, 0.f);
                unsigned pk = (unsigned short)f2bf(acc0) |
                              ((unsigned)(unsigned short)f2bf(acc1) << 16);
                *(unsigned*)&s_h1[t][h] = pk;
            }
        }
        __syncthreads();

        // ---- Phase 2: h2 = relu(h1 @ W2 + b2), MFMA, -> bf16 LDS ----
        // (all loop bounds/indices compile-time -> acc stays in registers)
        {
            floatx4 acc[4][4] = {};
            int row  = lane & 15;
            int quad = lane >> 4;
#pragma unroll
            for (int ks = 0; ks < 4; ++ks) {
                int koff = ks * 32 + quad * 8;
                short8 afr[4];
#pragma unroll
                for (int mt = 0; mt < 4; ++mt)
                    afr[mt] = *(const short8*)&s_h1[mt * 16 + row][koff];
                short8 bfr[4];
#pragma unroll
                for (int nl = 0; nl < 4; ++nl) {
                    int nt = wv * 4 + nl;
                    bfr[nl] = *(const short8*)&w2sw[(size_t)(((a * 16 + nt) * 4 + ks) * 64 + lane) * 8];
                }
#pragma unroll
                for (int mt = 0; mt < 4; ++mt)
#pragma unroll
                    for (int nl = 0; nl < 4; ++nl)
                        acc[mt][nl] = mfma16x16x32(afr[mt], bfr[nl], acc[mt][nl]);
            }
            // D: col = lane&15, row = quad*4 + r
#pragma unroll
            for (int nl = 0; nl < 4; ++nl) {
                int col = (wv * 4 + nl) * 16 + row;
                float bias = b2[a * H_ + col];
#pragma unroll
                for (int mt = 0; mt < 4; ++mt)
#pragma unroll
                    for (int r = 0; r < 4; ++r) {
                        int trow = mt * 16 + quad * 4 + r;
                        float v = acc[mt][nl][r] + bias;
                        s_h2[trow][col] = f2bf(fmaxf(v, 0.f));
                    }
            }
        }
        __syncthreads();

        // ---- Phase 3: out = h2 @ W3 + b3, MFMA -> LDS staging ----
        // R8: ALL accumulator indices compile-time. Waves cover nt = wv+4q
        // (q=0..2, nt 0..11); tile 12 in separate acc3[] on wave 0 only
        // (wave-uniform branch, compile-time indices -> no scratch).
        {
            int row  = lane & 15;
            int quad = lane >> 4;
            floatx4 acc[4][3] = {};
            floatx4 acc3[4]   = {};
#pragma unroll 2
            for (int ks = 0; ks < 8; ++ks) {
                int koff = ks * 32 + quad * 8;
                short8 afr[4];
#pragma unroll
                for (int mt = 0; mt < 4; ++mt)
                    afr[mt] = *(const short8*)&s_h2[mt * 16 + row][koff];
#pragma unroll
                for (int q = 0; q < 3; ++q) {
                    int nt = wv + q * 4;
                    short8 bfr = *(const short8*)&w3sw[(size_t)(((a * NT3 + nt) * 8 + ks) * 64 + lane) * 8];
#pragma unroll
                    for (int mt = 0; mt < 4; ++mt)
                        acc[mt][q] = mfma16x16x32(afr[mt], bfr, acc[mt][q]);
                }
                if (wv == 0) {
                    short8 bfr = *(const short8*)&w3sw[(size_t)(((a * NT3 + 12) * 8 + ks) * 64 + lane) * 8];
#pragma unroll
                    for (int mt = 0; mt < 4; ++mt)
                        acc3[mt] = mfma16x16x32(afr[mt], bfr, acc3[mt]);
                }
            }
            __syncthreads();   // all h2 reads done; smem is reused as outbuf below

#pragma unroll
            for (int q = 0; q < 3; ++q) {
                int col = (wv + q * 4) * 16 + row;   // <= 191 < 200 always
                float bias = b3[a * F_ + col];
#pragma unroll
                for (int mt = 0; mt < 4; ++mt)
#pragma unroll
                    for (int r = 0; r < 4; ++r) {
                        int trow = mt * 16 + quad * 4 + r;
                        s_ob[trow][col] = acc[mt][q][r] + bias;
                    }
            }
            if (wv == 0) {
                int col = 192 + row;
                if (col < F_) {
                    float bias = b3[a * F_ + col];
#pragma unroll
                    for (int mt = 0; mt < 4; ++mt)
#pragma unroll
                        for (int r = 0; r < 4; ++r) {
                            int trow = mt * 16 + quad * 4 + r;
                            s_ob[trow][col] = acc3[mt][r] + bias;
                        }
                }
            }
        }
        __syncthreads();

        // ---- Phase 4: cooperative contiguous store: 64 rows x 200 floats ----
        for (int i = tid; i < TT * 50; i += 256) {
            int t  = i / 50;
            int c4 = (i - t * 50) * 4;
            floatx4 v = *(const floatx4*)&s_ob[t][c4];
            *(floatx4*)&out[((size_t)(t0 + t) * A_ + a) * F_ + c4] = v;
        }
        __syncthreads();   // s_ob fully consumed before next a's gather overwrites smem
    }
}

extern "C" void kernel_launch(void* const* d_in, const int* in_sizes, int n_in,
                              void* d_out, int out_size, void* d_ws, size_t ws_size,
                              hipStream_t stream) {
    (void)in_sizes; (void)n_in; (void)out_size; (void)ws_size;
    const float* x  = (const float*)d_in[0];
    const float* W1 = (const float*)d_in[1];
    const float* b1 = (const float*)d_in[2];
    const float* W2 = (const float*)d_in[3];
    const float* b2 = (const float*)d_in[4];
    const float* W3 = (const float*)d_in[5];
    const float* b3 = (const float*)d_in[6];
    const int*   idx = (const int*)d_in[7];
    float* out = (float*)d_out;

    short* w2sw = (short*)d_ws;                                  // 655,360 B
    short* w3sw = w2sw + (size_t)A_ * 16 * 4 * 64 * 8;           // +1,064,960 B

    const int nconv = A_ * 16 * 4 * 64 + A_ * NT3 * 8 * 64;      // 107,520
    swizzle_weights<<<dim3((nconv + 255) / 256), dim3(256), 0, stream>>>(W2, W3, w2sw, w3sw);
    multidecoder_kernel<<<dim3(BT_ / TT), dim3(256), 0, stream>>>(
        x, W1, b1, b2, b3, idx, w2sw, w3sw, out);
}